// Round 3
// baseline (830.916 us; speedup 1.0000x reference)
//
#include <hip/hip_runtime.h>
#include <hip/hip_bf16.h>
#include <stdint.h>

// Problem: B=256, P=196, ENC=2048, DEC=512, ATT=512. ALL tensors fp32 on device
// (reference is jnp.float32 throughout; R1/R2 NaN was caused by misreading fp32
// as bf16 pairs -> random-exponent garbage -> inf att -> softmax NaN).
// Pipeline:
//   k0: transpose+convert W_enc fp32[2048][512] -> W_encT bf16[512][2048] (d_ws)
//   k1: comb[b][a] = dec[b]·W_dec[:,a] + b_dec[a] + b_enc[a]  (exact fp32, d_ws)
//   k2: att[b*196+p] = sum_a relu(enc[b,p]·W_enc[:,a] + comb[b][a]) * W_full[a]
//       A-tile converted fp32->bf16 (RNE) in regs during staging; bf16 MFMA,
//       fp32 accum. (b_full omitted: softmax shift-invariant.)
//   k3: alpha = softmax_P(att); context = sum_p alpha[p]*enc[b,p,:]  (pure fp32)

using u16x8 = __attribute__((ext_vector_type(8))) unsigned short;
using s16x8 = __attribute__((ext_vector_type(8))) short;
using f32x4 = __attribute__((ext_vector_type(4))) float;

static __device__ __forceinline__ unsigned short f2b(float f) {  // RNE fp32->bf16
  unsigned int u = __builtin_bit_cast(unsigned int, f);
  u = u + 0x7fffu + ((u >> 16) & 1u);
  return (unsigned short)(u >> 16);
}

// ---------------------------------------------------------------- k0: transpose+cvt
__global__ __launch_bounds__(256) void transpose_wenc(
    const float* __restrict__ wenc, unsigned short* __restrict__ wencT) {
  __shared__ unsigned short tile[32][34];  // +2 pad breaks bank stride
  const int t = threadIdx.x;
  const int x = t & 31, y = t >> 5;
  const int kb = blockIdx.x & 63, nb = blockIdx.x >> 6;
  const int k0 = kb << 5, n0 = nb << 5;
#pragma unroll
  for (int i = 0; i < 4; ++i) {
    int kk = y * 4 + i;
    tile[x][kk] = f2b(wenc[(size_t)(k0 + kk) * 512 + n0 + x]);
  }
  __syncthreads();
#pragma unroll
  for (int i = 0; i < 4; ++i) {
    int nn = y * 4 + i;
    wencT[(size_t)(n0 + nn) * 2048 + k0 + x] = tile[nn][x];
  }
}

// ---------------------------------------------------------------- k1: comb bias (fp32)
__global__ __launch_bounds__(256) void comb_kernel(
    const float* __restrict__ dec, const float* __restrict__ wdec,
    const float* __restrict__ bdec, const float* __restrict__ benc,
    float* __restrict__ comb) {
  __shared__ float dec_sh[8][512];
  const int t = threadIdx.x;
  const int b0 = blockIdx.x * 8;
  for (int i = t; i < 8 * 512; i += 256)
    dec_sh[i >> 9][i & 511] = dec[(size_t)b0 * 512 + i];
  __syncthreads();
  const int a0 = 2 * t;
  float bias0 = bdec[a0] + benc[a0];
  float bias1 = bdec[a0 + 1] + benc[a0 + 1];
  float acc0[8], acc1[8];
#pragma unroll
  for (int i = 0; i < 8; ++i) { acc0[i] = bias0; acc1[i] = bias1; }
  for (int e = 0; e < 512; ++e) {
    float2 wv = *(const float2*)&wdec[(size_t)e * 512 + a0];
#pragma unroll
    for (int i = 0; i < 8; ++i) {
      float d = dec_sh[i][e];
      acc0[i] = fmaf(d, wv.x, acc0[i]);
      acc1[i] = fmaf(d, wv.y, acc1[i]);
    }
  }
#pragma unroll
  for (int i = 0; i < 8; ++i) {
    float2 o = make_float2(acc0[i], acc1[i]);
    *(float2*)&comb[(size_t)(b0 + i) * 512 + a0] = o;
  }
}

// ---------------------------------------------------------------- k2: MFMA GEMM
// Tile: M_TILE=64 rows x N=512 full x K-step=32. 512 threads = 8 waves (2m x 4n).
// LDS rows padded to 40 ushorts (80 B): 16B-aligned, 2-way bank alias (free, m136).
#define LROW 40

__global__ __launch_bounds__(512, 4) void gemm_att(
    const float* __restrict__ enc, const unsigned short* __restrict__ wencT,
    const float* __restrict__ comb, const float* __restrict__ wfull_g,
    float* __restrict__ att) {
  __shared__ alignas(16) unsigned short Ash[64 * LROW];    // 5 KB
  __shared__ alignas(16) unsigned short Bsh[512 * LROW];   // 40 KB
  __shared__ float comb_sh[1024];
  __shared__ float wfull_sh[512];
  __shared__ float att_sh[64];

  const int t = threadIdx.x;
  const int l = t & 63;
  const int w = t >> 6;
  const int quad = l >> 4, col = l & 15;
  const int wm = w >> 2, wn = w & 3;
  const int r0 = blockIdx.x * 64;
  const int b0 = r0 / 196;
  const int rsw = (b0 + 1) * 196;  // rows >= rsw belong to batch b0+1
  const int b1 = (b0 + 1 < 256) ? b0 + 1 : 255;

  comb_sh[t] = comb[(size_t)b0 * 512 + t];
  comb_sh[512 + t] = comb[(size_t)b1 * 512 + t];
  wfull_sh[t] = wfull_g[t];
  if (t < 64) att_sh[t] = 0.0f;

  // ---- staging pointers (bump by 32 elements per K-step)
  // A (fp32): 256 chunks of 8 floats (64 rows x 4 chunks); threads 0..255.
  const float* agp = enc + (size_t)(r0 + ((t & 255) >> 2)) * 2048 + (t & 3) * 8;
  unsigned short* alp = &Ash[((t & 255) >> 2) * LROW + (t & 3) * 8];
  // B (bf16): 2048 chunks (512 rows x 4 chunks); all 512 threads x 4.
  const unsigned short* bgp[4];
  unsigned short* blp[4];
#pragma unroll
  for (int j = 0; j < 4; ++j) {
    int c = j * 512 + t;
    int n = c >> 2, kc = c & 3;
    bgp[j] = wencT + (size_t)n * 2048 + kc * 8;
    blp[j] = &Bsh[n * LROW + kc * 8];
  }

  // ---- fragment LDS offsets (ushort units), loop-invariant
  // A frag: A[m=col][k=quad*8+j]; B frag: B[n=col][k=quad*8+j] (B^T layout).
  int aoff[2], boff[8];
#pragma unroll
  for (int mt = 0; mt < 2; ++mt) {
    int ml = wm * 32 + mt * 16 + col;
    aoff[mt] = ml * LROW + quad * 8;
  }
#pragma unroll
  for (int nt = 0; nt < 8; ++nt) {
    int nl = wn * 128 + nt * 16 + col;
    boff[nt] = nl * LROW + quad * 8;
  }

  f32x4 acc[2][8];
#pragma unroll
  for (int mt = 0; mt < 2; ++mt)
#pragma unroll
    for (int nt = 0; nt < 8; ++nt) acc[mt][nt] = (f32x4){0.f, 0.f, 0.f, 0.f};

  for (int ks = 0; ks < 64; ++ks) {
    // issue global loads into regs first (overlaps prev iter's MFMA)
    f32x4 a0v, a1v;
    if (t < 256) {
      a0v = *(const f32x4*)agp;
      a1v = *(const f32x4*)(agp + 4);
    }
    u16x8 bv[4];
#pragma unroll
    for (int j = 0; j < 4; ++j) bv[j] = *(const u16x8*)bgp[j];

    __syncthreads();  // prev iteration's frag reads done
    if (t < 256) {
      u16x8 av;
      av[0] = f2b(a0v[0]); av[1] = f2b(a0v[1]);
      av[2] = f2b(a0v[2]); av[3] = f2b(a0v[3]);
      av[4] = f2b(a1v[0]); av[5] = f2b(a1v[1]);
      av[6] = f2b(a1v[2]); av[7] = f2b(a1v[3]);
      *(u16x8*)alp = av;
    }
#pragma unroll
    for (int j = 0; j < 4; ++j) *(u16x8*)blp[j] = bv[j];
    __syncthreads();  // LDS tile visible

    s16x8 afr[2];
#pragma unroll
    for (int mt = 0; mt < 2; ++mt) afr[mt] = *(const s16x8*)&Ash[aoff[mt]];
#pragma unroll
    for (int nt = 0; nt < 8; ++nt) {
      s16x8 bfr = *(const s16x8*)&Bsh[boff[nt]];
      acc[0][nt] = __builtin_amdgcn_mfma_f32_16x16x32_bf16(afr[0], bfr, acc[0][nt], 0, 0, 0);
      acc[1][nt] = __builtin_amdgcn_mfma_f32_16x16x32_bf16(afr[1], bfr, acc[1][nt], 0, 0, 0);
    }

    agp += 32;
#pragma unroll
    for (int j = 0; j < 4; ++j) bgp[j] += 32;
  }

  // ---- epilogue: v = relu(C + comb[b][n]); att_row += v * W_full[n]
  __syncthreads();
#pragma unroll
  for (int mt = 0; mt < 2; ++mt) {
#pragma unroll
    for (int r = 0; r < 4; ++r) {
      int rl = wm * 32 + mt * 16 + quad * 4 + r;  // C/D: row=quad*4+reg
      int cb = ((r0 + rl) >= rsw) ? 512 : 0;
      float s = 0.f;
#pragma unroll
      for (int nt = 0; nt < 8; ++nt) {
        int n = wn * 128 + nt * 16 + col;  // C/D: col=lane&15
        float v = acc[mt][nt][r] + comb_sh[cb + n];
        v = fmaxf(v, 0.f);
        s = fmaf(v, wfull_sh[n], s);
      }
      s += __shfl_xor(s, 1);
      s += __shfl_xor(s, 2);
      s += __shfl_xor(s, 4);
      s += __shfl_xor(s, 8);
      if (col == 0) atomicAdd(&att_sh[rl], s);
    }
  }
  __syncthreads();
  if (t < 64) att[(size_t)r0 + t] = att_sh[t];
}

// ---------------------------------------------------------------- k3: softmax+context (fp32)
__global__ __launch_bounds__(256) void softmax_ctx(
    const float* __restrict__ att, const float* __restrict__ enc,
    float* __restrict__ ctx_out, float* __restrict__ alpha_out) {
  const int b = blockIdx.x, t = threadIdx.x;
  __shared__ float red[256];
  __shared__ float alpha_sh[196];

  float v = (t < 196) ? att[(size_t)b * 196 + t] : -1e30f;
  red[t] = v;
  __syncthreads();
  for (int s = 128; s > 0; s >>= 1) {
    if (t < s) red[t] = fmaxf(red[t], red[t + s]);
    __syncthreads();
  }
  float mx = red[0];
  __syncthreads();
  float e = (t < 196) ? __expf(v - mx) : 0.f;
  red[t] = e;
  __syncthreads();
  for (int s = 128; s > 0; s >>= 1) {
    if (t < s) red[t] += red[t + s];
    __syncthreads();
  }
  float a = e / red[0];
  if (t < 196) {
    alpha_sh[t] = a;
    alpha_out[(size_t)b * 196 + t] = a;
  }
  __syncthreads();

  float acc[8] = {0.f, 0.f, 0.f, 0.f, 0.f, 0.f, 0.f, 0.f};
  const float* ep = enc + (size_t)b * 196 * 2048 + t * 8;
#pragma unroll 2
  for (int p = 0; p < 196; ++p) {
    float ap = alpha_sh[p];
    f32x4 e0 = *(const f32x4*)(ep);
    f32x4 e1 = *(const f32x4*)(ep + 4);
    acc[0] = fmaf(ap, e0[0], acc[0]);
    acc[1] = fmaf(ap, e0[1], acc[1]);
    acc[2] = fmaf(ap, e0[2], acc[2]);
    acc[3] = fmaf(ap, e0[3], acc[3]);
    acc[4] = fmaf(ap, e1[0], acc[4]);
    acc[5] = fmaf(ap, e1[1], acc[5]);
    acc[6] = fmaf(ap, e1[2], acc[6]);
    acc[7] = fmaf(ap, e1[3], acc[7]);
    ep += 2048;
  }
  float* op = ctx_out + (size_t)b * 2048 + t * 8;
  *(f32x4*)op = (f32x4){acc[0], acc[1], acc[2], acc[3]};
  *(f32x4*)(op + 4) = (f32x4){acc[4], acc[5], acc[6], acc[7]};
}

// ---------------------------------------------------------------- launch
extern "C" void kernel_launch(void* const* d_in, const int* in_sizes, int n_in,
                              void* d_out, int out_size, void* d_ws, size_t ws_size,
                              hipStream_t stream) {
  (void)in_sizes; (void)n_in; (void)out_size; (void)ws_size;
  const float* enc   = (const float*)d_in[0];  // [256,196,2048] fp32
  const float* dec   = (const float*)d_in[1];  // [256,512]
  const float* wenc  = (const float*)d_in[2];  // [2048,512]
  const float* benc  = (const float*)d_in[3];  // [512]
  const float* wdec  = (const float*)d_in[4];  // [512,512]
  const float* bdec  = (const float*)d_in[5];  // [512]
  const float* wfull = (const float*)d_in[6];  // [512]
  // d_in[7] (b_full) unused: softmax is shift-invariant.

  unsigned short* wencT = (unsigned short*)d_ws;                              // 2 MB
  float* comb = (float*)((char*)d_ws + (2u << 20));                           // 512 KB
  float* att  = (float*)((char*)d_ws + (2u << 20) + (512u << 10));            // 200 KB

  float* ctx_out = (float*)d_out;                    // [256,2048] fp32
  float* alpha_out = ctx_out + (size_t)256 * 2048;   // [256,196]  fp32

  hipLaunchKernelGGL(transpose_wenc, dim3(1024), dim3(256), 0, stream, wenc, wencT);
  hipLaunchKernelGGL(comb_kernel, dim3(32), dim3(256), 0, stream, dec, wdec, bdec, benc, comb);
  hipLaunchKernelGGL(gemm_att, dim3(784), dim3(512), 0, stream, enc, wencT, comb, wfull, att);
  hipLaunchKernelGGL(softmax_ctx, dim3(256), dim3(256), 0, stream, att, enc, ctx_out, alpha_out);
}